// Round 6
// baseline (342.298 us; speedup 1.0000x reference)
//
#include <hip/hip_runtime.h>
#include <stdint.h>

typedef unsigned short u16;

#define NROWS    16384
#define C_DIM    1024
#define DFF      4096
#define TILE_UP  1024
#define TILE_OUT 256
#define CSTR     16      // counter stride in ints (64 B / cacheline per gate counter)

using short8 = __attribute__((ext_vector_type(8))) short;
using f32x4  = __attribute__((ext_vector_type(4))) float;

// pack two f32 -> two bf16 (RTZ) in one v_perm_b32
__device__ __forceinline__ unsigned pk2(float lo, float hi) {
  union { float f; unsigned u; } L, H; L.f = lo; H.f = hi;
  return __builtin_amdgcn_perm(H.u, L.u, 0x07060302u);
}
// single f32 -> bf16 RNE
__device__ __forceinline__ u16 f2bf(float f) {
  union { float f; unsigned u; } v; v.f = f;
  return (u16)((v.u + 0x7FFFu + ((v.u >> 16) & 1u)) >> 16);
}

// async global->LDS, 16B/lane. Global addr may be per-lane (gather); LDS side is
// wave-uniform base, lane i lands at lp + 16*i.
__device__ __forceinline__ void glds16(const u16* gp, u16* lp) {
  __builtin_amdgcn_global_load_lds((const __attribute__((address_space(1))) void*)gp,
                                   (__attribute__((address_space(3))) void*)lp,
                                   16, 0, 0);
}

// zero counters + convert W_up (full) and W_down (gated slices) to bf16 in ws
__global__ void k_init(const float* __restrict__ Wup, const float* __restrict__ Wdn,
                       u16* __restrict__ wup16, u16* __restrict__ wdn16,
                       int* __restrict__ cnt) {
  const int t = blockIdx.x * 256 + threadIdx.x;
  if (blockIdx.x == 0 && threadIdx.x < 4 * CSTR) cnt[threadIdx.x] = 0;
  if (t < 524288) {                      // W_up: 4096*1024 / 8 per thread
    float4 f0 = ((const float4*)Wup)[t * 2];
    float4 f1 = ((const float4*)Wup)[t * 2 + 1];
    uint4 v; v.x = pk2(f0.x, f0.y); v.y = pk2(f0.z, f0.w);
             v.z = pk2(f1.x, f1.y); v.w = pk2(f1.z, f1.w);
    ((uint4*)wup16)[t] = v;
  } else {                               // W_down gated slices: [4][256][1024] / 8
    int t2 = t - 524288;                 // < 131072
    int e  = t2 << 3;
    int g  = e >> 18, rem = e & 262143;
    int r  = rem >> 10, k = rem & 1023;
    const float* src = Wdn + (size_t)(g * TILE_OUT + r) * DFF + g * TILE_UP + k;
    float4 f0 = *(const float4*)src;
    float4 f1 = *(const float4*)(src + 4);
    uint4 v; v.x = pk2(f0.x, f0.y); v.y = pk2(f0.z, f0.w);
             v.z = pk2(f1.x, f1.y); v.w = pk2(f1.z, f1.w);
    ((uint4*)wdn16)[t2] = v;
  }
}

// 64 rows/block, 4 rows in flight per wave (16 lanes per row). Gate logits (f32),
// argmax -> bucket (LDS-aggregated, 4 strided global atomics/block), one-hot out,
// AND x->bf16 into the FIRST half of each f32 out-row.
__global__ void k_gate(const float* __restrict__ x, const float* __restrict__ wg,
                       const float* __restrict__ bg, float* __restrict__ gate_out,
                       u16* __restrict__ xb,     // = (u16*)out; row n at xb + n*2048
                       int* __restrict__ cnt, int* __restrict__ rowlist) {
  __shared__ int lcnt[4], lbase[4];
  __shared__ unsigned char lgi[64];
  __shared__ unsigned char lpi[64];

  const int tid = threadIdx.x;
  if (tid < 4) lcnt[tid] = 0;
  __syncthreads();

  const int w = tid >> 6, lane = tid & 63;
  const int sub = lane >> 4, li = lane & 15;
#pragma unroll
  for (int p = 0; p < 4; ++p) {
    const int r = (w << 4) + (p << 2) + sub;       // row in block
    const int n = (blockIdx.x << 6) + r;
    const float4* xr = (const float4*)(x + (size_t)n * C_DIM);
    u16* xrow = xb + (size_t)n * 2048;
    float s0 = 0.f, s1 = 0.f, s2 = 0.f, s3 = 0.f;
#pragma unroll
    for (int k = 0; k < 16; ++k) {
      const int c4 = li + (k << 4);                // float4 index 0..255
      float4 xv = xr[c4];
      uint2 pp; pp.x = pk2(xv.x, xv.y); pp.y = pk2(xv.z, xv.w);
      *(uint2*)(xrow + (c4 << 2)) = pp;
      float4 w0 = ((const float4*)(wg + 0 * C_DIM))[c4];
      float4 w1 = ((const float4*)(wg + 1 * C_DIM))[c4];
      float4 w2 = ((const float4*)(wg + 2 * C_DIM))[c4];
      float4 w3 = ((const float4*)(wg + 3 * C_DIM))[c4];
      s0 += xv.x * w0.x + xv.y * w0.y + xv.z * w0.z + xv.w * w0.w;
      s1 += xv.x * w1.x + xv.y * w1.y + xv.z * w1.z + xv.w * w1.w;
      s2 += xv.x * w2.x + xv.y * w2.y + xv.z * w2.z + xv.w * w2.w;
      s3 += xv.x * w3.x + xv.y * w3.y + xv.z * w3.z + xv.w * w3.w;
    }
#pragma unroll
    for (int off = 8; off > 0; off >>= 1) {        // reduce within 16-lane group
      s0 += __shfl_xor(s0, off, 64);
      s1 += __shfl_xor(s1, off, 64);
      s2 += __shfl_xor(s2, off, 64);
      s3 += __shfl_xor(s3, off, 64);
    }
    if (li == 0) {
      float v0 = s0 + bg[0], v1 = s1 + bg[1], v2 = s2 + bg[2], v3 = s3 + bg[3];
      int g = 0; float best = v0;
      if (v1 > best) { best = v1; g = 1; }
      if (v2 > best) { best = v2; g = 2; }
      if (v3 > best) { best = v3; g = 3; }       // strict > == first max (np.argmax)
      int pos = atomicAdd(&lcnt[g], 1);
      lgi[r] = (unsigned char)g;
      lpi[r] = (unsigned char)pos;
      float4 oh;
      oh.x = (g == 0) ? 1.f : 0.f;
      oh.y = (g == 1) ? 1.f : 0.f;
      oh.z = (g == 2) ? 1.f : 0.f;
      oh.w = (g == 3) ? 1.f : 0.f;
      *(float4*)(gate_out + (size_t)n * 4) = oh;
    }
  }
  __syncthreads();
  if (tid < 4) lbase[tid] = atomicAdd(&cnt[tid * CSTR], lcnt[tid]);
  __syncthreads();
  if (tid < 64) {
    int g = lgi[tid];
    rowlist[g * NROWS + lbase[g] + lpi[tid]] = (blockIdx.x << 6) + tid;
  }
}

// grouped GEMM: hid16[n,0:1024] = relu(x_bf16[n] @ Wup16[g*1024+:,:]^T + b_up)
// BM=128, BN=256, BK=32; 512 thr = 8 waves (2m x 4n, 64x64 each). XCD-swizzled grid:
// id = xcd + 8*(nb + 4*mq) so the 4 nb-blocks of one m-tile run back-to-back per XCD.
__global__ void __launch_bounds__(512)
k_up(const u16* __restrict__ xb, const u16* __restrict__ wup16,
     const float* __restrict__ bup, u16* __restrict__ hid16,
     const int* __restrict__ cnt, const int* __restrict__ rowlist) {
  const int g = blockIdx.y;
  const int id = blockIdx.x;
  const int nb = (id >> 3) & 3;
  const int mtile = ((id >> 5) << 3) | (id & 7);   // 0..127
  const int count = cnt[g * CSTR];
  const int m_base = mtile << 7;
  if (m_base >= count) return;

  __shared__ __align__(16) u16 lA[128 * 32];
  __shared__ __align__(16) u16 lB[256 * 32];
  __shared__ int lrow[128];

  const int tid = threadIdx.x;
  if (tid < 128) {
    int idx = m_base + tid;
    lrow[tid] = rowlist[g * NROWS + (idx < count ? idx : count - 1)];
  }
  __syncthreads();

  const int w = tid >> 6, lane = tid & 63;
  const int srow = tid >> 2;             // 0..127
  const int scol = (tid & 3) << 3;
  const u16* pa  = xb + (size_t)lrow[srow] * 2048 + scol;   // x_bf16 row stride 2048 u16
  const u16* wbB = wup16 + ((size_t)g * TILE_UP + (size_t)nb * 256) * C_DIM;
  const u16* pb0 = wbB + (size_t)srow         * C_DIM + scol;
  const u16* pb1 = wbB + (size_t)(srow + 128) * C_DIM + scol;
  u16* la  = &lA[(w << 4) * 32];
  u16* lb0 = &lB[(w << 4) * 32];
  u16* lb1 = &lB[((w << 4) + 128) * 32];

  const int wm = (w >> 2) << 6, wn = (w & 3) << 6;
  const int fr = lane & 15, fq = lane >> 4;

  const f32x4 zero = {0.f, 0.f, 0.f, 0.f};
  f32x4 acc[4][4];
#pragma unroll
  for (int mi = 0; mi < 4; ++mi)
#pragma unroll
    for (int ni = 0; ni < 4; ++ni) acc[mi][ni] = zero;

  for (int k0 = 0; k0 < C_DIM; k0 += 32) {
    __syncthreads();
    glds16(pa + k0, la);
    glds16(pb0 + k0, lb0);
    glds16(pb1 + k0, lb1);
    __syncthreads();
    short8 af[4], bf[4];
#pragma unroll
    for (int mi = 0; mi < 4; ++mi)
      af[mi] = *(const short8*)&lA[(wm + mi * 16 + fr) * 32 + fq * 8];
#pragma unroll
    for (int ni = 0; ni < 4; ++ni)
      bf[ni] = *(const short8*)&lB[(wn + ni * 16 + fr) * 32 + fq * 8];
#pragma unroll
    for (int mi = 0; mi < 4; ++mi)
#pragma unroll
      for (int ni = 0; ni < 4; ++ni)
        acc[mi][ni] = __builtin_amdgcn_mfma_f32_16x16x32_bf16(af[mi], bf[ni], acc[mi][ni], 0, 0, 0);
  }

  // epilogue: C/D layout col=lane&15, row=(lane>>4)*4+reg; hid16 row stride 1024 u16
  const int cb = nb * 256 + wn;
  float bias[4];
#pragma unroll
  for (int ni = 0; ni < 4; ++ni)
    bias[ni] = bup[g * TILE_UP + cb + ni * 16 + fr];
  const int rb = fq << 2;
#pragma unroll
  for (int mi = 0; mi < 4; ++mi) {
#pragma unroll
    for (int reg = 0; reg < 4; ++reg) {
      int r = wm + mi * 16 + rb + reg;
      if (m_base + r < count) {
        u16* hrow = hid16 + (size_t)lrow[r] * 1024 + cb;
#pragma unroll
        for (int ni = 0; ni < 4; ++ni) {
          float v = acc[mi][ni][reg] + bias[ni];
          v = v > 0.f ? v : 0.f;
          hrow[wn - wn + ni * 16 + fr] = f2bf(v);   // hrow already at cb
        }
      }
    }
  }
}

// grouped GEMM: out[n, g*256 + nb*128 + c] = hid16[n,:] @ wdn16[g][nb*128+c,:]^T + b_down
// BM=64, BN=128, BK=32; 4 waves each 64x32. nb==0 blocks also zero the 768 non-gated cols.
// XCD-swizzled grid: id = xcd + 8*(nb + 2*mq).
__global__ void __launch_bounds__(256, 2)
k_down(const u16* __restrict__ hid16, const u16* __restrict__ wdn16,
       const float* __restrict__ bdn, float* __restrict__ out,
       const int* __restrict__ cnt, const int* __restrict__ rowlist) {
  const int g = blockIdx.y;
  const int id = blockIdx.x;
  const int nb = (id >> 3) & 1;
  const int mtile = ((id >> 4) << 3) | (id & 7);   // 0..255
  const int count = cnt[g * CSTR];
  const int m_base = mtile << 6;
  if (m_base >= count) return;

  __shared__ __align__(16) u16 lA[64 * 32];
  __shared__ __align__(16) u16 lB[128 * 32];
  __shared__ int lrow[64];

  const int tid = threadIdx.x;
  if (tid < 64) {
    int idx = m_base + tid;
    lrow[tid] = rowlist[g * NROWS + (idx < count ? idx : count - 1)];
  }
  __syncthreads();

  const int w = tid >> 6, lane = tid & 63;
  const int srow = (w << 4) + (lane >> 2);
  const int scol = (lane & 3) << 3;
  const u16* pa  = hid16 + (size_t)lrow[srow] * 1024 + scol;
  const u16* wbB = wdn16 + (size_t)(g * TILE_OUT + nb * 128) * TILE_UP;
  const u16* pb0 = wbB + (size_t)srow        * TILE_UP + scol;
  const u16* pb1 = wbB + (size_t)(srow + 64) * TILE_UP + scol;
  u16* la  = &lA[(w << 4) * 32];
  u16* lb0 = &lB[(w << 4) * 32];
  u16* lb1 = &lB[(64 + (w << 4)) * 32];

  const int wn = w << 5;               // wave n-slice (32 cols); rows 0..63 shared
  const int fr = lane & 15, fq = lane >> 4;

  const f32x4 zero = {0.f, 0.f, 0.f, 0.f};
  f32x4 acc[4][2];
#pragma unroll
  for (int mi = 0; mi < 4; ++mi)
#pragma unroll
    for (int ni = 0; ni < 2; ++ni) acc[mi][ni] = zero;

  for (int k0 = 0; k0 < TILE_UP; k0 += 32) {
    __syncthreads();
    glds16(pa + k0, la);
    glds16(pb0 + k0, lb0);
    glds16(pb1 + k0, lb1);
    __syncthreads();
    short8 af[4], bf[2];
#pragma unroll
    for (int mi = 0; mi < 4; ++mi)
      af[mi] = *(const short8*)&lA[(mi * 16 + fr) * 32 + fq * 8];
#pragma unroll
    for (int ni = 0; ni < 2; ++ni)
      bf[ni] = *(const short8*)&lB[(wn + ni * 16 + fr) * 32 + fq * 8];
#pragma unroll
    for (int mi = 0; mi < 4; ++mi)
#pragma unroll
      for (int ni = 0; ni < 2; ++ni)
        acc[mi][ni] = __builtin_amdgcn_mfma_f32_16x16x32_bf16(af[mi], bf[ni], acc[mi][ni], 0, 0, 0);
  }

  // nb==0: zero the 768 non-gated f32 cols of our valid rows (disjoint from gated cols)
  if (nb == 0) {
    const uint4 z4 = {0u, 0u, 0u, 0u};
    for (int i = tid; i < 64 * 192; i += 256) {
      int r = i / 192, u = i - r * 192;
      if (m_base + r < count) {
        int c = u << 2;
        if (c >= g * TILE_OUT) c += TILE_OUT;
        *(uint4*)(out + (size_t)lrow[r] * C_DIM + c) = z4;
      }
    }
  }

  float bias[2];
  const int cb = g * TILE_OUT + nb * 128 + wn;
#pragma unroll
  for (int ni = 0; ni < 2; ++ni)
    bias[ni] = bdn[cb + ni * 16 + fr];
  const int rb = fq << 2;
#pragma unroll
  for (int mi = 0; mi < 4; ++mi) {
#pragma unroll
    for (int reg = 0; reg < 4; ++reg) {
      int r = mi * 16 + rb + reg;
      if (m_base + r < count) {
        float* orow = out + (size_t)lrow[r] * C_DIM + cb;
#pragma unroll
        for (int ni = 0; ni < 2; ++ni)
          orow[ni * 16 + fr] = acc[mi][ni][reg] + bias[ni];
      }
    }
  }
}

extern "C" void kernel_launch(void* const* d_in, const int* in_sizes, int n_in,
                              void* d_out, int out_size, void* d_ws, size_t ws_size,
                              hipStream_t stream) {
  const float* x   = (const float*)d_in[0];
  const float* wg  = (const float*)d_in[1];
  const float* bg  = (const float*)d_in[2];
  const float* wup = (const float*)d_in[3];
  const float* bup = (const float*)d_in[4];
  const float* wdn = (const float*)d_in[5];
  const float* bdn = (const float*)d_in[6];
  float* out      = (float*)d_out;
  float* gate_out = out + (size_t)NROWS * C_DIM;

  char* ws = (char*)d_ws;
  int* cnt     = (int*)ws;                          // 256 B
  int* rowlist = (int*)(ws + 4096);                 // 256 KB
  u16* wup16   = (u16*)(ws + (1u << 20));           // 8 MB  [1 MB, 9 MB)
  u16* wdn16   = (u16*)(ws + 9u * (1u << 20));      // 2 MB  [9 MB, 11 MB)
  u16* hid16   = (u16*)(ws + 16u * (1u << 20));     // 32 MB [16 MB, 48 MB)

  k_init<<<2560, 256, 0, stream>>>(wup, wdn, wup16, wdn16, cnt);
  // x_bf16 -> first half of each out f32 row; final k_down overwrites all of out
  k_gate<<<NROWS / 64, 256, 0, stream>>>(x, wg, bg, gate_out, (u16*)out, cnt, rowlist);
  k_up  <<<dim3(512, 4), 512, 0, stream>>>((const u16*)out, wup16, bup, hid16, cnt, rowlist);
  k_down<<<dim3(512, 4), 256, 0, stream>>>(hid16, wdn16, bdn, out, cnt, rowlist);
}

// Round 7
// 255.227 us; speedup vs baseline: 1.3412x; 1.3412x over previous
//
#include <hip/hip_runtime.h>
#include <stdint.h>

typedef unsigned short u16;

#define NROWS    16384
#define C_DIM    1024
#define DFF      4096
#define TILE_UP  1024
#define TILE_OUT 256
#define CSTR     16      // counter stride in ints (64 B / cacheline per gate counter)

using short8 = __attribute__((ext_vector_type(8))) short;
using f32x4  = __attribute__((ext_vector_type(4))) float;

// pack two f32 -> two bf16 (RTZ) in one v_perm_b32
__device__ __forceinline__ unsigned pk2(float lo, float hi) {
  union { float f; unsigned u; } L, H; L.f = lo; H.f = hi;
  return __builtin_amdgcn_perm(H.u, L.u, 0x07060302u);
}
// single f32 -> bf16 RNE
__device__ __forceinline__ u16 f2bf(float f) {
  union { float f; unsigned u; } v; v.f = f;
  return (u16)((v.u + 0x7FFFu + ((v.u >> 16) & 1u)) >> 16);
}

// async global->LDS, 16B/lane. Global addr may be per-lane (gather); LDS side is
// wave-uniform base, lane i lands at lp + 16*i.
__device__ __forceinline__ void glds16(const u16* gp, u16* lp) {
  __builtin_amdgcn_global_load_lds((const __attribute__((address_space(1))) void*)gp,
                                   (__attribute__((address_space(3))) void*)lp,
                                   16, 0, 0);
}

// zero counters + convert W_up (full) and W_down (gated slices) to bf16 in ws
__global__ void k_init(const float* __restrict__ Wup, const float* __restrict__ Wdn,
                       u16* __restrict__ wup16, u16* __restrict__ wdn16,
                       int* __restrict__ cnt) {
  const int t = blockIdx.x * 256 + threadIdx.x;
  if (blockIdx.x == 0 && threadIdx.x < 4 * CSTR) cnt[threadIdx.x] = 0;
  if (t < 524288) {                      // W_up: 4096*1024 / 8 per thread
    float4 f0 = ((const float4*)Wup)[t * 2];
    float4 f1 = ((const float4*)Wup)[t * 2 + 1];
    uint4 v; v.x = pk2(f0.x, f0.y); v.y = pk2(f0.z, f0.w);
             v.z = pk2(f1.x, f1.y); v.w = pk2(f1.z, f1.w);
    ((uint4*)wup16)[t] = v;
  } else {                               // W_down gated slices: [4][256][1024] / 8
    int t2 = t - 524288;                 // < 131072
    int e  = t2 << 3;
    int g  = e >> 18, rem = e & 262143;
    int r  = rem >> 10, k = rem & 1023;
    const float* src = Wdn + (size_t)(g * TILE_OUT + r) * DFF + g * TILE_UP + k;
    float4 f0 = *(const float4*)src;
    float4 f1 = *(const float4*)(src + 4);
    uint4 v; v.x = pk2(f0.x, f0.y); v.y = pk2(f0.z, f0.w);
             v.z = pk2(f1.x, f1.y); v.w = pk2(f1.z, f1.w);
    ((uint4*)wdn16)[t2] = v;
  }
}

// 64 rows/block, block=1024 (16 waves/CU for latency hiding), wave-per-row x4.
// Gate logits (f32) -> argmax bucket (LDS-aggregated, 4 strided global atomics/block),
// one-hot gate out, AND x->bf16 into the FIRST half of each f32 out-row.
__global__ void __launch_bounds__(1024)
k_gate(const float* __restrict__ x, const float* __restrict__ wg,
       const float* __restrict__ bg, float* __restrict__ gate_out,
       u16* __restrict__ xb,     // = (u16*)out; row n at xb + n*2048
       int* __restrict__ cnt, int* __restrict__ rowlist) {
  __shared__ int lcnt[4], lbase[4];
  __shared__ unsigned char lgi[64];
  __shared__ unsigned char lpi[64];

  const int tid = threadIdx.x;
  if (tid < 4) lcnt[tid] = 0;
  __syncthreads();

  const int w = tid >> 6, lane = tid & 63;
  for (int i = 0; i < 4; ++i) {
    const int r = (w << 2) + i;                  // row within block (w*4+i)
    const int n = (blockIdx.x << 6) + r;
    const float4* xr = (const float4*)(x + (size_t)n * C_DIM);
    u16* xrow = xb + (size_t)n * 2048;
    float s0 = 0.f, s1 = 0.f, s2 = 0.f, s3 = 0.f;
#pragma unroll
    for (int it = 0; it < 4; ++it) {
      int c4 = lane + (it << 6);
      float4 xv = xr[c4];
      uint2 p; p.x = pk2(xv.x, xv.y); p.y = pk2(xv.z, xv.w);
      *(uint2*)(xrow + (c4 << 2)) = p;           // 512 B contiguous per wave-instr
      float4 w0 = ((const float4*)(wg + 0 * C_DIM))[c4];
      float4 w1 = ((const float4*)(wg + 1 * C_DIM))[c4];
      float4 w2 = ((const float4*)(wg + 2 * C_DIM))[c4];
      float4 w3 = ((const float4*)(wg + 3 * C_DIM))[c4];
      s0 += xv.x * w0.x + xv.y * w0.y + xv.z * w0.z + xv.w * w0.w;
      s1 += xv.x * w1.x + xv.y * w1.y + xv.z * w1.z + xv.w * w1.w;
      s2 += xv.x * w2.x + xv.y * w2.y + xv.z * w2.z + xv.w * w2.w;
      s3 += xv.x * w3.x + xv.y * w3.y + xv.z * w3.z + xv.w * w3.w;
    }
#pragma unroll
    for (int off = 32; off > 0; off >>= 1) {
      s0 += __shfl_down(s0, off, 64);
      s1 += __shfl_down(s1, off, 64);
      s2 += __shfl_down(s2, off, 64);
      s3 += __shfl_down(s3, off, 64);
    }
    if (lane == 0) {
      float v0 = s0 + bg[0], v1 = s1 + bg[1], v2 = s2 + bg[2], v3 = s3 + bg[3];
      int g = 0; float best = v0;
      if (v1 > best) { best = v1; g = 1; }
      if (v2 > best) { best = v2; g = 2; }
      if (v3 > best) { best = v3; g = 3; }       // strict > == first max (np.argmax)
      int pos = atomicAdd(&lcnt[g], 1);
      lgi[r] = (unsigned char)g;
      lpi[r] = (unsigned char)pos;
      float4 oh;
      oh.x = (g == 0) ? 1.f : 0.f;
      oh.y = (g == 1) ? 1.f : 0.f;
      oh.z = (g == 2) ? 1.f : 0.f;
      oh.w = (g == 3) ? 1.f : 0.f;
      *(float4*)(gate_out + (size_t)n * 4) = oh;
    }
  }
  __syncthreads();
  if (tid < 4) lbase[tid] = atomicAdd(&cnt[tid * CSTR], lcnt[tid]);
  __syncthreads();
  if (tid < 64) {
    int g = lgi[tid];
    rowlist[g * NROWS + lbase[g] + lpi[tid]] = (blockIdx.x << 6) + tid;
  }
}

// grouped GEMM: hid16[n,0:1024] = relu(x_bf16[n] @ Wup16[g*1024+:,:]^T + b_up)
// BM=128, BN=256, BK=32; 512 thr = 8 waves (2m x 4n, 64x64 each). XCD-swizzled grid:
// id = xcd + 8*(nb + 4*mq) so the 4 nb-blocks of one m-tile run on the same XCD.
__global__ void __launch_bounds__(512)
k_up(const u16* __restrict__ xb, const u16* __restrict__ wup16,
     const float* __restrict__ bup, u16* __restrict__ hid16,
     const int* __restrict__ cnt, const int* __restrict__ rowlist) {
  const int g = blockIdx.y;
  const int id = blockIdx.x;
  const int nb = (id >> 3) & 3;
  const int mtile = ((id >> 5) << 3) | (id & 7);   // 0..127
  const int count = cnt[g * CSTR];
  const int m_base = mtile << 7;
  if (m_base >= count) return;

  __shared__ __align__(16) u16 lA[128 * 32];
  __shared__ __align__(16) u16 lB[256 * 32];
  __shared__ int lrow[128];

  const int tid = threadIdx.x;
  if (tid < 128) {
    int idx = m_base + tid;
    lrow[tid] = rowlist[g * NROWS + (idx < count ? idx : count - 1)];
  }
  __syncthreads();

  const int w = tid >> 6, lane = tid & 63;
  const int srow = tid >> 2;             // 0..127
  const int scol = (tid & 3) << 3;
  const u16* pa  = xb + (size_t)lrow[srow] * 2048 + scol;   // x_bf16 row stride 2048 u16
  const u16* wbB = wup16 + ((size_t)g * TILE_UP + (size_t)nb * 256) * C_DIM;
  const u16* pb0 = wbB + (size_t)srow         * C_DIM + scol;
  const u16* pb1 = wbB + (size_t)(srow + 128) * C_DIM + scol;
  u16* la  = &lA[(w << 4) * 32];
  u16* lb0 = &lB[(w << 4) * 32];
  u16* lb1 = &lB[((w << 4) + 128) * 32];

  const int wm = (w >> 2) << 6, wn = (w & 3) << 6;
  const int fr = lane & 15, fq = lane >> 4;

  const f32x4 zero = {0.f, 0.f, 0.f, 0.f};
  f32x4 acc[4][4];
#pragma unroll
  for (int mi = 0; mi < 4; ++mi)
#pragma unroll
    for (int ni = 0; ni < 4; ++ni) acc[mi][ni] = zero;

  for (int k0 = 0; k0 < C_DIM; k0 += 32) {
    __syncthreads();
    glds16(pa + k0, la);
    glds16(pb0 + k0, lb0);
    glds16(pb1 + k0, lb1);
    __syncthreads();
    short8 af[4], bf[4];
#pragma unroll
    for (int mi = 0; mi < 4; ++mi)
      af[mi] = *(const short8*)&lA[(wm + mi * 16 + fr) * 32 + fq * 8];
#pragma unroll
    for (int ni = 0; ni < 4; ++ni)
      bf[ni] = *(const short8*)&lB[(wn + ni * 16 + fr) * 32 + fq * 8];
#pragma unroll
    for (int mi = 0; mi < 4; ++mi)
#pragma unroll
      for (int ni = 0; ni < 4; ++ni)
        acc[mi][ni] = __builtin_amdgcn_mfma_f32_16x16x32_bf16(af[mi], bf[ni], acc[mi][ni], 0, 0, 0);
  }

  // epilogue: C/D layout col=lane&15, row=(lane>>4)*4+reg; hid16 row stride 1024 u16
  const int cb = nb * 256 + wn;
  float bias[4];
#pragma unroll
  for (int ni = 0; ni < 4; ++ni)
    bias[ni] = bup[g * TILE_UP + cb + ni * 16 + fr];
  const int rb = fq << 2;
#pragma unroll
  for (int mi = 0; mi < 4; ++mi) {
#pragma unroll
    for (int reg = 0; reg < 4; ++reg) {
      int r = wm + mi * 16 + rb + reg;
      if (m_base + r < count) {
        u16* hrow = hid16 + (size_t)lrow[r] * 1024 + cb;
#pragma unroll
        for (int ni = 0; ni < 4; ++ni) {
          float v = acc[mi][ni][reg] + bias[ni];
          v = v > 0.f ? v : 0.f;
          hrow[ni * 16 + fr] = f2bf(v);
        }
      }
    }
  }
}

// grouped GEMM: out[n, g*256 + nb*128 + c] = hid16[n,:] @ wdn16[g][nb*128+c,:]^T + b_down
// BM=64, BN=128, BK=32; 4 waves each 64x32. nb==0 blocks also zero the 768 non-gated cols.
// XCD-swizzled grid: id = xcd + 8*(nb + 2*mq).
__global__ void __launch_bounds__(256, 2)
k_down(const u16* __restrict__ hid16, const u16* __restrict__ wdn16,
       const float* __restrict__ bdn, float* __restrict__ out,
       const int* __restrict__ cnt, const int* __restrict__ rowlist) {
  const int g = blockIdx.y;
  const int id = blockIdx.x;
  const int nb = (id >> 3) & 1;
  const int mtile = ((id >> 4) << 3) | (id & 7);   // 0..255
  const int count = cnt[g * CSTR];
  const int m_base = mtile << 6;
  if (m_base >= count) return;

  __shared__ __align__(16) u16 lA[64 * 32];
  __shared__ __align__(16) u16 lB[128 * 32];
  __shared__ int lrow[64];

  const int tid = threadIdx.x;
  if (tid < 64) {
    int idx = m_base + tid;
    lrow[tid] = rowlist[g * NROWS + (idx < count ? idx : count - 1)];
  }
  __syncthreads();

  const int w = tid >> 6, lane = tid & 63;
  const int srow = (w << 4) + (lane >> 2);
  const int scol = (lane & 3) << 3;
  const u16* pa  = hid16 + (size_t)lrow[srow] * 1024 + scol;
  const u16* wbB = wdn16 + (size_t)(g * TILE_OUT + nb * 128) * TILE_UP;
  const u16* pb0 = wbB + (size_t)srow        * TILE_UP + scol;
  const u16* pb1 = wbB + (size_t)(srow + 64) * TILE_UP + scol;
  u16* la  = &lA[(w << 4) * 32];
  u16* lb0 = &lB[(w << 4) * 32];
  u16* lb1 = &lB[(64 + (w << 4)) * 32];

  const int wn = w << 5;               // wave n-slice (32 cols); rows 0..63 shared
  const int fr = lane & 15, fq = lane >> 4;

  const f32x4 zero = {0.f, 0.f, 0.f, 0.f};
  f32x4 acc[4][2];
#pragma unroll
  for (int mi = 0; mi < 4; ++mi)
#pragma unroll
    for (int ni = 0; ni < 2; ++ni) acc[mi][ni] = zero;

  for (int k0 = 0; k0 < TILE_UP; k0 += 32) {
    __syncthreads();
    glds16(pa + k0, la);
    glds16(pb0 + k0, lb0);
    glds16(pb1 + k0, lb1);
    __syncthreads();
    short8 af[4], bf[2];
#pragma unroll
    for (int mi = 0; mi < 4; ++mi)
      af[mi] = *(const short8*)&lA[(mi * 16 + fr) * 32 + fq * 8];
#pragma unroll
    for (int ni = 0; ni < 2; ++ni)
      bf[ni] = *(const short8*)&lB[(wn + ni * 16 + fr) * 32 + fq * 8];
#pragma unroll
    for (int mi = 0; mi < 4; ++mi)
#pragma unroll
      for (int ni = 0; ni < 2; ++ni)
        acc[mi][ni] = __builtin_amdgcn_mfma_f32_16x16x32_bf16(af[mi], bf[ni], acc[mi][ni], 0, 0, 0);
  }

  // nb==0: zero the 768 non-gated f32 cols of our valid rows (disjoint from gated cols)
  if (nb == 0) {
    const uint4 z4 = {0u, 0u, 0u, 0u};
    for (int i = tid; i < 64 * 192; i += 256) {
      int r = i / 192, u = i - r * 192;
      if (m_base + r < count) {
        int c = u << 2;
        if (c >= g * TILE_OUT) c += TILE_OUT;
        *(uint4*)(out + (size_t)lrow[r] * C_DIM + c) = z4;
      }
    }
  }

  float bias[2];
  const int cb = g * TILE_OUT + nb * 128 + wn;
#pragma unroll
  for (int ni = 0; ni < 2; ++ni)
    bias[ni] = bdn[cb + ni * 16 + fr];
  const int rb = fq << 2;
#pragma unroll
  for (int mi = 0; mi < 4; ++mi) {
#pragma unroll
    for (int reg = 0; reg < 4; ++reg) {
      int r = mi * 16 + rb + reg;
      if (m_base + r < count) {
        float* orow = out + (size_t)lrow[r] * C_DIM + cb;
#pragma unroll
        for (int ni = 0; ni < 2; ++ni)
          orow[ni * 16 + fr] = acc[mi][ni][reg] + bias[ni];
      }
    }
  }
}

extern "C" void kernel_launch(void* const* d_in, const int* in_sizes, int n_in,
                              void* d_out, int out_size, void* d_ws, size_t ws_size,
                              hipStream_t stream) {
  const float* x   = (const float*)d_in[0];
  const float* wg  = (const float*)d_in[1];
  const float* bg  = (const float*)d_in[2];
  const float* wup = (const float*)d_in[3];
  const float* bup = (const float*)d_in[4];
  const float* wdn = (const float*)d_in[5];
  const float* bdn = (const float*)d_in[6];
  float* out      = (float*)d_out;
  float* gate_out = out + (size_t)NROWS * C_DIM;

  char* ws = (char*)d_ws;
  int* cnt     = (int*)ws;                          // 256 B
  int* rowlist = (int*)(ws + 4096);                 // 256 KB
  u16* wup16   = (u16*)(ws + (1u << 20));           // 8 MB  [1 MB, 9 MB)
  u16* wdn16   = (u16*)(ws + 9u * (1u << 20));      // 2 MB  [9 MB, 11 MB)
  u16* hid16   = (u16*)(ws + 16u * (1u << 20));     // 32 MB [16 MB, 48 MB)

  k_init<<<2560, 256, 0, stream>>>(wup, wdn, wup16, wdn16, cnt);
  // x_bf16 -> first half of each out f32 row; final k_down overwrites all of out
  k_gate<<<NROWS / 64, 1024, 0, stream>>>(x, wg, bg, gate_out, (u16*)out, cnt, rowlist);
  k_up  <<<dim3(512, 4), 512, 0, stream>>>((const u16*)out, wup16, bup, hid16, cnt, rowlist);
  k_down<<<dim3(512, 4), 256, 0, stream>>>(hid16, wdn16, bdn, out, cnt, rowlist);
}